// Round 3
// baseline (17130.626 us; speedup 1.0000x reference)
//
#include <hip/hip_runtime.h>
#include <hip/hip_bf16.h>

// BiLSTM(512/dir, T=8192) + linear(9) + Viterbi decode.
//  K1 gemm_xproj : xproj[t, 0..4095] = emb[sentence[t]] @ [Wih_f;Wih_b]^T + (bih+bhh)
//  K2 lstm_scan  : 64 persistent blocks (32/dir) x 320 threads.
//                  wave0 = coordinator (gates, c-state, h store);
//                  waves 1..4 = k-chunks of 128, Whh slice in VGPRs (128 fp32/lane).
//                  NO barriers in the step loop: u64 poison-poll (agent relaxed atomics),
//                  wave-local LDS staging (lgkmcnt), monotonic LDS counter (rel/acq),
//                  own-slice forwarded through LDS (skips self L3 round trip).
//  K3 feats      : feats[t,n] = [h_f|h_b] @ W_out^T + b_out
//  K4 viterbi    : single wave; backpointers packed 4b x 9 into u64/step.
//
// ws layout (floats):
//   [0)                 xprojb   8192*4096            = 128 MB
//   [+8192*4096)        h_seq    2*8192*512           =  32 MB (poisoned 0x7F each launch)
//   [+2*8192*512)       feats    8192*9
//   [then]              bpw      8192 u64

#define T_SEQ   8192
#define EMB     512
#define HDIM    512
#define NSUB    32                      // blocks per direction
#define SLICE   16                      // h floats produced per block
#define POISON64 0x7F7F7F7F7F7F7F7Full  // |h|<1 so never produced

// ---------------------------------------------------------------- K1: GEMM
__global__ __launch_bounds__(256) void gemm_xproj(
    const int* __restrict__ sentence, const float* __restrict__ emb,
    const float* __restrict__ Wih_f, const float* __restrict__ Wih_b,
    const float* __restrict__ bih_f, const float* __restrict__ bhh_f,
    const float* __restrict__ bih_b, const float* __restrict__ bhh_b,
    float* __restrict__ xprojb)
{
    __shared__ float As[16][68];
    __shared__ float Bs[16][68];
    __shared__ int   srow[64];

    const int tid = threadIdx.x;
    const int bm = blockIdx.x;          // 128 tiles of t
    const int bn = blockIdx.y;          // 64 tiles of j (0..31 fwd, 32..63 bwd)
    const int fwd = (bn < 32);
    const float* W = fwd ? Wih_f : Wih_b;
    const int jbase = fwd ? bn * 64 : bn * 64 - 2048;

    if (tid < 64) srow[tid] = sentence[bm * 64 + tid];
    __syncthreads();

    const int tx = tid & 15, ty = tid >> 4;
    const int lkk = tid & 15;
    const int lr  = tid >> 4;
    int sr[4];
    #pragma unroll
    for (int i = 0; i < 4; ++i) sr[i] = srow[lr + i * 16];

    float acc[4][4] = {};

    for (int kb = 0; kb < 32; ++kb) {
        const int k0 = kb * 16;
        #pragma unroll
        for (int i = 0; i < 4; ++i) {
            const int r = lr + i * 16;
            As[lkk][r] = emb[(size_t)sr[i] * EMB + k0 + lkk];
            Bs[lkk][r] = W[(size_t)(jbase + r) * EMB + k0 + lkk];
        }
        __syncthreads();
        #pragma unroll
        for (int kk = 0; kk < 16; ++kk) {
            const float4 a = *(const float4*)&As[kk][ty * 4];
            const float4 b = *(const float4*)&Bs[kk][tx * 4];
            acc[0][0] = fmaf(a.x, b.x, acc[0][0]); acc[0][1] = fmaf(a.x, b.y, acc[0][1]);
            acc[0][2] = fmaf(a.x, b.z, acc[0][2]); acc[0][3] = fmaf(a.x, b.w, acc[0][3]);
            acc[1][0] = fmaf(a.y, b.x, acc[1][0]); acc[1][1] = fmaf(a.y, b.y, acc[1][1]);
            acc[1][2] = fmaf(a.y, b.z, acc[1][2]); acc[1][3] = fmaf(a.y, b.w, acc[1][3]);
            acc[2][0] = fmaf(a.z, b.x, acc[2][0]); acc[2][1] = fmaf(a.z, b.y, acc[2][1]);
            acc[2][2] = fmaf(a.z, b.z, acc[2][2]); acc[2][3] = fmaf(a.z, b.w, acc[2][3]);
            acc[3][0] = fmaf(a.w, b.x, acc[3][0]); acc[3][1] = fmaf(a.w, b.y, acc[3][1]);
            acc[3][2] = fmaf(a.w, b.z, acc[3][2]); acc[3][3] = fmaf(a.w, b.w, acc[3][3]);
        }
        __syncthreads();
    }

    const float* b1 = fwd ? bih_f : bih_b;
    const float* b2 = fwd ? bhh_f : bhh_b;
    const int jj = jbase + tx * 4;
    const float4 bias = make_float4(b1[jj] + b2[jj], b1[jj + 1] + b2[jj + 1],
                                    b1[jj + 2] + b2[jj + 2], b1[jj + 3] + b2[jj + 3]);
    #pragma unroll
    for (int i = 0; i < 4; ++i) {
        const int t = bm * 64 + ty * 4 + i;
        float4 v = make_float4(acc[i][0] + bias.x, acc[i][1] + bias.y,
                               acc[i][2] + bias.z, acc[i][3] + bias.w);
        *(float4*)&xprojb[(size_t)t * 4096 + bn * 64 + tx * 4] = v;
    }
}

// ------------------------------------------------------------- K2: LSTM scan
__device__ __forceinline__ float fsig(float x) { return 1.0f / (1.0f + __expf(-x)); }
__device__ __forceinline__ float ftanh(float x) {
    const float e = __expf(-2.0f * fabsf(x));
    return copysignf((1.0f - e) / (1.0f + e), x);
}
__device__ __forceinline__ unsigned long long pack2(float a, float b) {
    return (unsigned long long)__float_as_uint(a) |
           ((unsigned long long)__float_as_uint(b) << 32);
}

__global__ __launch_bounds__(320, 1) void lstm_scan(
    const float* __restrict__ xprojb,
    const float* __restrict__ Whh_f, const float* __restrict__ Whh_b,
    float* __restrict__ hseq)
{
    const int tid  = threadIdx.x;
    const int lane = tid & 63;
    const int wv   = tid >> 6;          // 0 = coordinator, 1..4 = k-chunk waves
    const int blk  = blockIdx.x;        // 0..63
    const int dir  = blk & 1;
    const int sub  = blk >> 1;          // 0..31
    const float* __restrict__ Whh = dir ? Whh_b : Whh_f;
    float* hs = hseq + (size_t)dir * T_SEQ * HDIM;

    __shared__ __align__(16) float hst[2][4][128];      // staged h chunks (per wave)
    __shared__ __align__(16) float partials[2][4][64];  // per-chunk row partial sums
    __shared__ __align__(8)  float ownh[2][SLICE];      // own slice LDS forward
    __shared__ unsigned int cnt;                        // monotonic: 4 per step
    __shared__ unsigned int ownflag;                    // monotonic: 1 per step

    if (tid == 0) { cnt = 0u; ownflag = 0u; }
    __syncthreads();   // the ONLY barrier in this kernel

    if (wv == 0) {
        // ---- coordinator wave: finalize gates, own c-state, publish h slice
        float c_state = 0.0f;
        const int  m   = lane & 15;
        const bool fin = lane < 16;
        #pragma unroll 1
        for (int s = 0; s < T_SEQ; ++s) {
            const int t = dir ? (T_SEQ - 1 - s) : s;
            const int p = s & 1;
            float xp0 = 0.f, xp1 = 0.f, xp2 = 0.f, xp3 = 0.f;
            if (fin) {   // issue early: latency hides under the spin
                const float* xr = xprojb + (size_t)t * 4096 + dir * 2048 + sub * SLICE + m;
                xp0 = xr[0]; xp1 = xr[512]; xp2 = xr[1024]; xp3 = xr[1536];
            }
            const unsigned target = 4u * (unsigned)(s + 1);
            while (__hip_atomic_load(&cnt, __ATOMIC_ACQUIRE,
                                     __HIP_MEMORY_SCOPE_WORKGROUP) < target) {}
            float h = 0.0f;
            if (fin) {
                const float si = partials[p][0][m]      + partials[p][1][m]
                               + partials[p][2][m]      + partials[p][3][m];
                const float sf = partials[p][0][16 + m] + partials[p][1][16 + m]
                               + partials[p][2][16 + m] + partials[p][3][16 + m];
                const float sg = partials[p][0][32 + m] + partials[p][1][32 + m]
                               + partials[p][2][32 + m] + partials[p][3][32 + m];
                const float so = partials[p][0][48 + m] + partials[p][1][48 + m]
                               + partials[p][2][48 + m] + partials[p][3][48 + m];
                const float i_ = fsig(si + xp0);
                const float f_ = fsig(sf + xp1);
                const float g_ = ftanh(sg + xp2);
                const float o_ = fsig(so + xp3);
                c_state = fmaf(f_, c_state, i_ * g_);
                h = o_ * ftanh(c_state);
                ownh[p][m] = h;
            }
            if (lane == 0)   // release orders the ownh writes of this wave
                __hip_atomic_store(&ownflag, (unsigned)(s + 1), __ATOMIC_RELEASE,
                                   __HIP_MEMORY_SCOPE_WORKGROUP);
            // pack h pairs and publish to global (u64 atomic -> no tearing)
            const float ha = __shfl(h, lane * 2);
            const float hb = __shfl(h, lane * 2 + 1);
            if (lane < 8) {
                unsigned long long* hp =
                    (unsigned long long*)(hs + (size_t)t * HDIM + sub * SLICE);
                __hip_atomic_store(hp + lane, pack2(ha, hb), __ATOMIC_RELAXED,
                                   __HIP_MEMORY_SCOPE_AGENT);
            }
        }
    } else {
        // ---- k-chunk wave: poll its 128 h values, partial matvec, ds partials
        const int c  = wv - 1;          // chunk 0..3, k in [128c, 128c+128)
        const int rp = lane & 31;       // row pair
        const int kh = lane >> 5;       // k half (64)
        const int r0 = rp * 2;          // block-local rows r0, r0+1 (same gate)
        const int grow  = (r0 >> 4) * 512 + sub * SLICE + (r0 & 15);
        const int kbase = c * 128 + kh * 64;
        float w0[64], w1[64];
        {
            const float* src0 = Whh + (size_t)grow * 512 + kbase;
            const float* src1 = src0 + 512;
            #pragma unroll
            for (int j = 0; j < 16; ++j) {
                const float4 a = *(const float4*)(src0 + 4 * j);
                const float4 b = *(const float4*)(src1 + 4 * j);
                w0[4*j] = a.x; w0[4*j+1] = a.y; w0[4*j+2] = a.z; w0[4*j+3] = a.w;
                w1[4*j] = b.x; w1[4*j+1] = b.y; w1[4*j+2] = b.z; w1[4*j+3] = b.w;
            }
        }
        // lanes whose u64 pair is produced by THIS block -> LDS fast path
        const bool ownlane = (c == (sub >> 3)) && ((lane >> 3) == (sub & 7));

        #pragma unroll 1
        for (int s = 0; s < T_SEQ; ++s) {
            const int t = dir ? (T_SEQ - 1 - s) : s;
            const int p = s & 1;
            float2 hv2;
            if (s == 0) {
                hv2 = make_float2(0.f, 0.f);
            } else if (ownlane) {
                while (__hip_atomic_load(&ownflag, __ATOMIC_ACQUIRE,
                                         __HIP_MEMORY_SCOPE_WORKGROUP) < (unsigned)s) {}
                const int pp = (s - 1) & 1;
                const int j  = lane & 7;
                hv2.x = ownh[pp][2 * j];
                hv2.y = ownh[pp][2 * j + 1];
            } else {
                const int tprev = dir ? (t + 1) : (t - 1);
                const unsigned long long* hp =
                    (const unsigned long long*)(hs + (size_t)tprev * HDIM) + c * 64 + lane;
                unsigned long long u = __hip_atomic_load(hp, __ATOMIC_RELAXED,
                                                         __HIP_MEMORY_SCOPE_AGENT);
                while (u == POISON64)
                    u = __hip_atomic_load(hp, __ATOMIC_RELAXED, __HIP_MEMORY_SCOPE_AGENT);
                hv2.x = __uint_as_float((unsigned)(u & 0xffffffffull));
                hv2.y = __uint_as_float((unsigned)(u >> 32));
            }
            ((float2*)&hst[p][c][0])[lane] = hv2;   // wave-local; lgkmcnt orders RAW

            float acc0 = 0.f, acc1 = 0.f;
            const float4* hb = (const float4*)&hst[p][c][kh * 64];
            #pragma unroll
            for (int j = 0; j < 16; ++j) {
                const float4 hv = hb[j];
                acc0 = fmaf(w0[4*j],   hv.x, acc0); acc1 = fmaf(w1[4*j],   hv.x, acc1);
                acc0 = fmaf(w0[4*j+1], hv.y, acc0); acc1 = fmaf(w1[4*j+1], hv.y, acc1);
                acc0 = fmaf(w0[4*j+2], hv.z, acc0); acc1 = fmaf(w1[4*j+2], hv.z, acc1);
                acc0 = fmaf(w0[4*j+3], hv.w, acc0); acc1 = fmaf(w1[4*j+3], hv.w, acc1);
            }
            acc0 += __shfl_xor(acc0, 32);
            acc1 += __shfl_xor(acc1, 32);
            if (lane < 32)
                ((float2*)&partials[p][c][0])[lane] = make_float2(acc0, acc1);
            if (lane == 0)   // release: waits this wave's ds writes first
                __hip_atomic_fetch_add(&cnt, 1u, __ATOMIC_RELEASE,
                                       __HIP_MEMORY_SCOPE_WORKGROUP);
        }
    }
}

// ---------------------------------------------------------------- K3: feats
__global__ __launch_bounds__(256) void feats_kernel(
    const float* __restrict__ hseq, const float* __restrict__ W_out,
    const float* __restrict__ b_out, float* __restrict__ feats)
{
    const int idx = blockIdx.x * 256 + threadIdx.x;   // (t, n)
    if (idx >= T_SEQ * 9) return;
    const int t = idx / 9;
    const int n = idx - t * 9;
    const float4* hf = (const float4*)(hseq + (size_t)t * HDIM);
    const float4* hb = (const float4*)(hseq + (size_t)(T_SEQ + t) * HDIM);
    const float4* wf = (const float4*)(W_out + (size_t)n * 1024);
    const float4* wb = wf + 128;
    float acc = b_out[n];
    #pragma unroll 8
    for (int i = 0; i < 128; ++i) {
        const float4 a = hf[i], w = wf[i];
        acc = fmaf(a.x, w.x, acc); acc = fmaf(a.y, w.y, acc);
        acc = fmaf(a.z, w.z, acc); acc = fmaf(a.w, w.w, acc);
    }
    #pragma unroll 8
    for (int i = 0; i < 128; ++i) {
        const float4 a = hb[i], w = wb[i];
        acc = fmaf(a.x, w.x, acc); acc = fmaf(a.y, w.y, acc);
        acc = fmaf(a.z, w.z, acc); acc = fmaf(a.w, w.w, acc);
    }
    feats[idx] = acc;
}

// --------------------------------------------------------------- K4: viterbi
__global__ __launch_bounds__(64) void viterbi_kernel(
    const float* __restrict__ feats, const float* __restrict__ trans,
    unsigned long long* __restrict__ bpw, float* __restrict__ out)
{
    const int lane = threadIdx.x;
    __shared__ __align__(16) float flds[1024 * 9];
    __shared__ unsigned char path_lds[T_SEQ];

    float tr[9];
    #pragma unroll
    for (int p = 0; p < 9; ++p) tr[p] = 0.f;
    float tstop = 0.f;
    if (lane < 9) {
        #pragma unroll
        for (int p = 0; p < 9; ++p) tr[p] = trans[lane * 9 + p];
        tstop = trans[8 * 9 + lane];
    }
    float fv = (lane == 7) ? 0.0f : -10000.0f;        // START_IDX = 7

    for (int ch = 0; ch < 8; ++ch) {
        const float4* src = (const float4*)(feats + (size_t)ch * 9216);
        #pragma unroll
        for (int i = 0; i < 36; ++i)
            ((float4*)flds)[lane + i * 64] = src[lane + i * 64];
        __syncthreads();

        for (int tt = 0; tt < 1024; ++tt) {
            const int t = ch * 1024 + tt;
            const float f0 = __shfl(fv, 0), f1 = __shfl(fv, 1), f2 = __shfl(fv, 2);
            const float f3 = __shfl(fv, 3), f4 = __shfl(fv, 4), f5 = __shfl(fv, 5);
            const float f6 = __shfl(fv, 6), f7 = __shfl(fv, 7), f8 = __shfl(fv, 8);
            const float s0 = f0 + tr[0], s1 = f1 + tr[1], s2 = f2 + tr[2];
            const float s3 = f3 + tr[3], s4 = f4 + tr[4], s5 = f5 + tr[5];
            const float s6 = f6 + tr[6], s7 = f7 + tr[7], s8 = f8 + tr[8];
            const float mx = fmaxf(fmaxf(fmaxf(fmaxf(s0, s1), fmaxf(s2, s3)),
                                         fmaxf(fmaxf(s4, s5), fmaxf(s6, s7))), s8);
            const unsigned bits =
                (s0 >= mx ? 1u : 0u)   | (s1 >= mx ? 2u : 0u)   | (s2 >= mx ? 4u : 0u) |
                (s3 >= mx ? 8u : 0u)   | (s4 >= mx ? 16u : 0u)  | (s5 >= mx ? 32u : 0u) |
                (s6 >= mx ? 64u : 0u)  | (s7 >= mx ? 128u : 0u) | (s8 >= mx ? 256u : 0u);
            const int bi = __ffs(bits) - 1;
            const float feat = (lane < 9) ? flds[tt * 9 + lane] : 0.0f;
            fv = mx + feat;
            const unsigned long long b0 = __ballot(bi & 1);
            const unsigned long long b1 = __ballot(bi & 2);
            const unsigned long long b2 = __ballot(bi & 4);
            const unsigned long long b3 = __ballot(bi & 8);
            if (lane == 0) {
                bpw[t] = (b0 & 511ull) | ((b1 & 511ull) << 9) |
                         ((b2 & 511ull) << 18) | ((b3 & 511ull) << 27);
            }
        }
        __syncthreads();
    }

    const float term = fv + tstop;
    const float t0 = __shfl(term, 0), t1 = __shfl(term, 1), t2 = __shfl(term, 2);
    const float t3 = __shfl(term, 3), t4 = __shfl(term, 4), t5 = __shfl(term, 5);
    const float t6 = __shfl(term, 6), t7 = __shfl(term, 7), t8 = __shfl(term, 8);
    const float mxt = fmaxf(fmaxf(fmaxf(fmaxf(t0, t1), fmaxf(t2, t3)),
                                  fmaxf(fmaxf(t4, t5), fmaxf(t6, t7))), t8);
    const unsigned bitst =
        (t0 >= mxt ? 1u : 0u)   | (t1 >= mxt ? 2u : 0u)   | (t2 >= mxt ? 4u : 0u) |
        (t3 >= mxt ? 8u : 0u)   | (t4 >= mxt ? 16u : 0u)  | (t5 >= mxt ? 32u : 0u) |
        (t6 >= mxt ? 64u : 0u)  | (t7 >= mxt ? 128u : 0u) | (t8 >= mxt ? 256u : 0u);
    const int best = __ffs(bitst) - 1;

    if (lane == 0) {
        out[0] = mxt;
        int c = best;
        path_lds[T_SEQ - 1] = (unsigned char)c;
        for (int thi = T_SEQ - 2; thi >= 15; thi -= 16) {
            const int tlo = thi - 15;
            unsigned long long wbuf[16];
            #pragma unroll
            for (int i = 0; i < 16; ++i) wbuf[i] = bpw[tlo + 1 + i];
            #pragma unroll
            for (int i = 15; i >= 0; --i) {
                const unsigned long long wv = wbuf[i];
                c = (int)((wv >> c) & 1ull) |
                    ((int)((wv >> (9 + c)) & 1ull) << 1) |
                    ((int)((wv >> (18 + c)) & 1ull) << 2) |
                    ((int)((wv >> (27 + c)) & 1ull) << 3);
                path_lds[tlo + i] = (unsigned char)c;
            }
        }
        for (int t2i = 14; t2i >= 0; --t2i) {
            const unsigned long long wv = bpw[t2i + 1];
            c = (int)((wv >> c) & 1ull) |
                ((int)((wv >> (9 + c)) & 1ull) << 1) |
                ((int)((wv >> (18 + c)) & 1ull) << 2) |
                ((int)((wv >> (27 + c)) & 1ull) << 3);
            path_lds[t2i] = (unsigned char)c;
        }
    }
    __syncthreads();
    #pragma unroll 4
    for (int i = 0; i < T_SEQ / 64; ++i) {
        const int t = i * 64 + lane;
        out[1 + t] = (float)path_lds[t];
    }
}

// ------------------------------------------------------------------- launch
extern "C" void kernel_launch(void* const* d_in, const int* in_sizes, int n_in,
                              void* d_out, int out_size, void* d_ws, size_t ws_size,
                              hipStream_t stream)
{
    (void)in_sizes; (void)n_in; (void)out_size; (void)ws_size;

    const int*   sentence = (const int*)  d_in[0];
    const float* emb      = (const float*)d_in[1];
    const float* Wih_f    = (const float*)d_in[2];
    const float* Whh_f    = (const float*)d_in[3];
    const float* bih_f    = (const float*)d_in[4];
    const float* bhh_f    = (const float*)d_in[5];
    const float* Wih_b    = (const float*)d_in[6];
    const float* Whh_b    = (const float*)d_in[7];
    const float* bih_b    = (const float*)d_in[8];
    const float* bhh_b    = (const float*)d_in[9];
    const float* W_out    = (const float*)d_in[10];
    const float* b_out    = (const float*)d_in[11];
    const float* trans    = (const float*)d_in[12];

    float* ws      = (float*)d_ws;
    float* xprojb  = ws;                                        // 8192*4096
    float* hseq    = ws + (size_t)T_SEQ * 4096;                 // 2*8192*512
    float* feats   = hseq + (size_t)2 * T_SEQ * HDIM;           // 8192*9
    unsigned long long* bpw = (unsigned long long*)(feats + (size_t)T_SEQ * 9);

    // re-poison the h exchange buffer every launch (graph replay safety)
    hipMemsetAsync(hseq, 0x7F, (size_t)2 * T_SEQ * HDIM * sizeof(float), stream);

    gemm_xproj<<<dim3(128, 64), 256, 0, stream>>>(
        sentence, emb, Wih_f, Wih_b, bih_f, bhh_f, bih_b, bhh_b, xprojb);

    lstm_scan<<<dim3(64), 320, 0, stream>>>(
        xprojb, Whh_f, Whh_b, hseq);

    feats_kernel<<<dim3((T_SEQ * 9 + 255) / 256), 256, 0, stream>>>(
        hseq, W_out, b_out, feats);

    viterbi_kernel<<<dim3(1), 64, 0, stream>>>(feats, trans, bpw, (float*)d_out);
}

// Round 4
// 16995.561 us; speedup vs baseline: 1.0079x; 1.0079x over previous
//
#include <hip/hip_runtime.h>
#include <hip/hip_bf16.h>

// BiLSTM(512/dir, T=8192) + linear(9) + Viterbi decode.
//  K1 gemm_xproj : 128x128 tile, 8x8 register blocking (VALU fp32; no fp32 MFMA on CDNA4)
//  K2 lstm_scan  : 64 persistent blocks (32/dir) x 320 threads.
//                  wave0 = coordinator (gates, c-state, h store);
//                  waves 1..4 = k-chunks of 128, Whh slice PINNED in VGPRs via inline-asm
//                  (128 fp32/lane; VGPR_Count must read ~190 — 80 means remat bug is back).
//                  NO barriers in the step loop: u64 poison-poll (agent relaxed atomics),
//                  wave-local LDS staging (lgkmcnt), monotonic LDS counter (rel/acq),
//                  own-slice forwarded through LDS.
//  K3 feats      : feats[t,n] = [h_f|h_b] @ W_out^T + b_out
//  K4 viterbi    : single wave; backpointers packed 4b x 9 into u64/step.
//
// ws layout (floats):
//   [0)                 xprojb   8192*4096            = 128 MB
//   [+8192*4096)        h_seq    2*8192*512           =  32 MB (poisoned 0x7F each launch)
//   [+2*8192*512)       feats    8192*9
//   [then]              bpw      8192 u64

#define T_SEQ   8192
#define EMB     512
#define HDIM    512
#define SLICE   16                      // h floats produced per block
#define POISON64 0x7F7F7F7F7F7F7F7Full  // |h|<1 so never produced

// ---------------------------------------------------------------- K1: GEMM
__global__ __launch_bounds__(256) void gemm_xproj(
    const int* __restrict__ sentence, const float* __restrict__ emb,
    const float* __restrict__ Wih_f, const float* __restrict__ Wih_b,
    const float* __restrict__ bih_f, const float* __restrict__ bhh_f,
    const float* __restrict__ bih_b, const float* __restrict__ bhh_b,
    float* __restrict__ xprojb)
{
    __shared__ float As[16][132];      // [kk][row], pad to 132 floats
    __shared__ float Bs[16][132];
    __shared__ int   srow[128];

    const int tid = threadIdx.x;
    const int bm = blockIdx.x;          // 64 tiles of 128 t
    const int bn = blockIdx.y;          // 32 tiles of 128 j (0..15 fwd, 16..31 bwd)
    const int fwd = (bn < 16);
    const float* __restrict__ W = fwd ? Wih_f : Wih_b;
    const int jbase = bn * 128 - (fwd ? 0 : 2048);

    if (tid < 128) srow[tid] = sentence[bm * 128 + tid];
    __syncthreads();

    const int lkk = tid & 15;           // staging k index
    const int lr  = tid >> 4;           // staging row group (8 rows)
    int sr[8];
    #pragma unroll
    for (int i = 0; i < 8; ++i) sr[i] = srow[lr * 8 + i];
    const float* wbase = W + (size_t)(jbase + lr * 8) * EMB + lkk;

    const int tx = tid & 15, ty = tid >> 4;
    float acc[8][8] = {};

    for (int kb = 0; kb < 32; ++kb) {
        const int k0 = kb * 16;
        #pragma unroll
        for (int i = 0; i < 8; ++i) {
            As[lkk][lr * 8 + i] = emb[(size_t)sr[i] * EMB + k0 + lkk];
            Bs[lkk][lr * 8 + i] = wbase[(size_t)i * EMB + k0];
        }
        __syncthreads();
        #pragma unroll
        for (int kk = 0; kk < 16; ++kk) {
            const float4 a0 = *(const float4*)&As[kk][ty * 8];
            const float4 a1 = *(const float4*)&As[kk][ty * 8 + 4];
            const float4 b0 = *(const float4*)&Bs[kk][tx * 8];
            const float4 b1 = *(const float4*)&Bs[kk][tx * 8 + 4];
            const float av[8] = {a0.x,a0.y,a0.z,a0.w,a1.x,a1.y,a1.z,a1.w};
            const float bv[8] = {b0.x,b0.y,b0.z,b0.w,b1.x,b1.y,b1.z,b1.w};
            #pragma unroll
            for (int i = 0; i < 8; ++i)
                #pragma unroll
                for (int j = 0; j < 8; ++j)
                    acc[i][j] = fmaf(av[i], bv[j], acc[i][j]);
        }
        __syncthreads();
    }

    const float* b1p = fwd ? bih_f : bih_b;
    const float* b2p = fwd ? bhh_f : bhh_b;
    float bias[8];
    #pragma unroll
    for (int j = 0; j < 8; ++j) {
        const int jj = jbase + tx * 8 + j;
        bias[j] = b1p[jj] + b2p[jj];
    }
    #pragma unroll
    for (int i = 0; i < 8; ++i) {
        const int t = bm * 128 + ty * 8 + i;
        float4* dst = (float4*)&xprojb[(size_t)t * 4096 + bn * 128 + tx * 8];
        dst[0] = make_float4(acc[i][0] + bias[0], acc[i][1] + bias[1],
                             acc[i][2] + bias[2], acc[i][3] + bias[3]);
        dst[1] = make_float4(acc[i][4] + bias[4], acc[i][5] + bias[5],
                             acc[i][6] + bias[6], acc[i][7] + bias[7]);
    }
}

// ------------------------------------------------------------- K2: LSTM scan
__device__ __forceinline__ float fsig(float x) { return 1.0f / (1.0f + __expf(-x)); }
__device__ __forceinline__ float ftanh(float x) {
    const float e = __expf(-2.0f * fabsf(x));
    return copysignf((1.0f - e) / (1.0f + e), x);
}
__device__ __forceinline__ unsigned long long pack2(float a, float b) {
    return (unsigned long long)__float_as_uint(a) |
           ((unsigned long long)__float_as_uint(b) << 32);
}

__global__ __launch_bounds__(320, 1) void lstm_scan(
    const float* __restrict__ xprojb,
    const float* __restrict__ Whh_f, const float* __restrict__ Whh_b,
    float* __restrict__ hseq)
{
    const int tid  = threadIdx.x;
    const int lane = tid & 63;
    const int wv   = tid >> 6;          // 0 = coordinator, 1..4 = k-chunk waves
    const int blk  = blockIdx.x;        // 0..63
    const int dir  = blk & 1;
    const int sub  = blk >> 1;          // 0..31
    const float* __restrict__ Whh = dir ? Whh_b : Whh_f;
    float* hs = hseq + (size_t)dir * T_SEQ * HDIM;

    __shared__ __align__(16) float hst[2][4][128];      // staged h chunks (per wave)
    __shared__ __align__(16) float partials[2][4][64];  // per-chunk row partial sums
    __shared__ __align__(8)  float ownh[2][SLICE];      // own slice LDS forward
    __shared__ unsigned int cnt;                        // monotonic: 4 per step
    __shared__ unsigned int ownflag;                    // monotonic: 1 per step

    if (tid == 0) { cnt = 0u; ownflag = 0u; }
    __syncthreads();   // the ONLY barrier in this kernel

    if (wv == 0) {
        // ---- coordinator wave: finalize gates, own c-state, publish h slice
        float c_state = 0.0f;
        const int  m   = lane & 15;
        const bool fin = lane < 16;
        #pragma unroll 1
        for (int s = 0; s < T_SEQ; ++s) {
            const int t = dir ? (T_SEQ - 1 - s) : s;
            const int p = s & 1;
            float xp0 = 0.f, xp1 = 0.f, xp2 = 0.f, xp3 = 0.f;
            if (fin) {   // issue early: latency hides under the spin
                const float* xr = xprojb + (size_t)t * 4096 + dir * 2048 + sub * SLICE + m;
                xp0 = xr[0]; xp1 = xr[512]; xp2 = xr[1024]; xp3 = xr[1536];
            }
            const unsigned target = 4u * (unsigned)(s + 1);
            while (__hip_atomic_load(&cnt, __ATOMIC_ACQUIRE,
                                     __HIP_MEMORY_SCOPE_WORKGROUP) < target) {}
            float h = 0.0f;
            if (fin) {
                const float si = partials[p][0][m]      + partials[p][1][m]
                               + partials[p][2][m]      + partials[p][3][m];
                const float sf = partials[p][0][16 + m] + partials[p][1][16 + m]
                               + partials[p][2][16 + m] + partials[p][3][16 + m];
                const float sg = partials[p][0][32 + m] + partials[p][1][32 + m]
                               + partials[p][2][32 + m] + partials[p][3][32 + m];
                const float so = partials[p][0][48 + m] + partials[p][1][48 + m]
                               + partials[p][2][48 + m] + partials[p][3][48 + m];
                const float i_ = fsig(si + xp0);
                const float f_ = fsig(sf + xp1);
                const float g_ = ftanh(sg + xp2);
                const float o_ = fsig(so + xp3);
                c_state = fmaf(f_, c_state, i_ * g_);
                h = o_ * ftanh(c_state);
                ownh[p][m] = h;
            }
            if (lane == 0)   // release orders the ownh writes of this wave
                __hip_atomic_store(&ownflag, (unsigned)(s + 1), __ATOMIC_RELEASE,
                                   __HIP_MEMORY_SCOPE_WORKGROUP);
            // pack h pairs and publish to global (u64 atomic -> no tearing)
            const float ha = __shfl(h, lane * 2);
            const float hb = __shfl(h, lane * 2 + 1);
            if (lane < 8) {
                unsigned long long* hp =
                    (unsigned long long*)(hs + (size_t)t * HDIM + sub * SLICE);
                __hip_atomic_store(hp + lane, pack2(ha, hb), __ATOMIC_RELAXED,
                                   __HIP_MEMORY_SCOPE_AGENT);
            }
        }
    } else {
        // ---- k-chunk wave: poll its 128 h values, partial matvec, ds partials
        const int c  = wv - 1;          // chunk 0..3, k in [128c, 128c+128)
        const int rp = lane & 31;       // row pair
        const int kh = lane >> 5;       // k half (64)
        const int r0 = rp * 2;          // block-local rows r0, r0+1 (same gate)
        const int grow  = (r0 >> 4) * 512 + sub * SLICE + (r0 & 15);
        const int kbase = c * 128 + kh * 64;
        float w0[64], w1[64];
        {
            const float* src0 = Whh + (size_t)grow * 512 + kbase;
            const float* src1 = src0 + 512;
            #pragma unroll
            for (int j = 0; j < 16; ++j) {
                const float4 a = *(const float4*)(src0 + 4 * j);
                const float4 b = *(const float4*)(src1 + 4 * j);
                w0[4*j] = a.x; w0[4*j+1] = a.y; w0[4*j+2] = a.z; w0[4*j+3] = a.w;
                w1[4*j] = b.x; w1[4*j+1] = b.y; w1[4*j+2] = b.z; w1[4*j+3] = b.w;
            }
        }
        // PIN the weight slice in VGPRs: values become inline-asm-defined, so the
        // backend cannot rematerialize the global loads inside the step loop.
        // (R2 bug: VGPR_Count=80 proved remat; weights re-streamed from L2 every step.)
        #pragma unroll
        for (int j = 0; j < 64; ++j) {
            asm volatile("" : "+v"(w0[j]));
            asm volatile("" : "+v"(w1[j]));
        }

        // lanes whose u64 pair is produced by THIS block -> LDS fast path
        const bool ownlane = (c == (sub >> 3)) && ((lane >> 3) == (sub & 7));

        #pragma unroll 1
        for (int s = 0; s < T_SEQ; ++s) {
            const int t = dir ? (T_SEQ - 1 - s) : s;
            const int p = s & 1;
            float2 hv2;
            if (s == 0) {
                hv2 = make_float2(0.f, 0.f);
            } else if (ownlane) {
                while (__hip_atomic_load(&ownflag, __ATOMIC_ACQUIRE,
                                         __HIP_MEMORY_SCOPE_WORKGROUP) < (unsigned)s) {}
                const int pp = (s - 1) & 1;
                const int j  = lane & 7;
                hv2.x = ownh[pp][2 * j];
                hv2.y = ownh[pp][2 * j + 1];
            } else {
                const int tprev = dir ? (t + 1) : (t - 1);
                const unsigned long long* hp =
                    (const unsigned long long*)(hs + (size_t)tprev * HDIM) + c * 64 + lane;
                unsigned long long u = __hip_atomic_load(hp, __ATOMIC_RELAXED,
                                                         __HIP_MEMORY_SCOPE_AGENT);
                while (u == POISON64)
                    u = __hip_atomic_load(hp, __ATOMIC_RELAXED, __HIP_MEMORY_SCOPE_AGENT);
                hv2.x = __uint_as_float((unsigned)(u & 0xffffffffull));
                hv2.y = __uint_as_float((unsigned)(u >> 32));
            }
            ((float2*)&hst[p][c][0])[lane] = hv2;   // wave-local; lgkmcnt orders RAW

            float acc0 = 0.f, acc1 = 0.f;
            const float4* hb = (const float4*)&hst[p][c][kh * 64];
            #pragma unroll
            for (int j = 0; j < 16; ++j) {
                const float4 hv = hb[j];
                acc0 = fmaf(w0[4*j],   hv.x, acc0); acc1 = fmaf(w1[4*j],   hv.x, acc1);
                acc0 = fmaf(w0[4*j+1], hv.y, acc0); acc1 = fmaf(w1[4*j+1], hv.y, acc1);
                acc0 = fmaf(w0[4*j+2], hv.z, acc0); acc1 = fmaf(w1[4*j+2], hv.z, acc1);
                acc0 = fmaf(w0[4*j+3], hv.w, acc0); acc1 = fmaf(w1[4*j+3], hv.w, acc1);
            }
            acc0 += __shfl_xor(acc0, 32);
            acc1 += __shfl_xor(acc1, 32);
            if (lane < 32)
                ((float2*)&partials[p][c][0])[lane] = make_float2(acc0, acc1);
            if (lane == 0)   // release: waits this wave's ds writes first
                __hip_atomic_fetch_add(&cnt, 1u, __ATOMIC_RELEASE,
                                       __HIP_MEMORY_SCOPE_WORKGROUP);
        }
    }
}

// ---------------------------------------------------------------- K3: feats
__global__ __launch_bounds__(256) void feats_kernel(
    const float* __restrict__ hseq, const float* __restrict__ W_out,
    const float* __restrict__ b_out, float* __restrict__ feats)
{
    const int idx = blockIdx.x * 256 + threadIdx.x;   // (t, n)
    if (idx >= T_SEQ * 9) return;
    const int t = idx / 9;
    const int n = idx - t * 9;
    const float4* hf = (const float4*)(hseq + (size_t)t * HDIM);
    const float4* hb = (const float4*)(hseq + (size_t)(T_SEQ + t) * HDIM);
    const float4* wf = (const float4*)(W_out + (size_t)n * 1024);
    const float4* wb = wf + 128;
    float acc = b_out[n];
    #pragma unroll 8
    for (int i = 0; i < 128; ++i) {
        const float4 a = hf[i], w = wf[i];
        acc = fmaf(a.x, w.x, acc); acc = fmaf(a.y, w.y, acc);
        acc = fmaf(a.z, w.z, acc); acc = fmaf(a.w, w.w, acc);
    }
    #pragma unroll 8
    for (int i = 0; i < 128; ++i) {
        const float4 a = hb[i], w = wb[i];
        acc = fmaf(a.x, w.x, acc); acc = fmaf(a.y, w.y, acc);
        acc = fmaf(a.z, w.z, acc); acc = fmaf(a.w, w.w, acc);
    }
    feats[idx] = acc;
}

// --------------------------------------------------------------- K4: viterbi
__global__ __launch_bounds__(64) void viterbi_kernel(
    const float* __restrict__ feats, const float* __restrict__ trans,
    unsigned long long* __restrict__ bpw, float* __restrict__ out)
{
    const int lane = threadIdx.x;
    __shared__ __align__(16) float flds[1024 * 9];
    __shared__ unsigned char path_lds[T_SEQ];

    float tr[9];
    #pragma unroll
    for (int p = 0; p < 9; ++p) tr[p] = 0.f;
    float tstop = 0.f;
    if (lane < 9) {
        #pragma unroll
        for (int p = 0; p < 9; ++p) tr[p] = trans[lane * 9 + p];
        tstop = trans[8 * 9 + lane];
    }
    float fv = (lane == 7) ? 0.0f : -10000.0f;        // START_IDX = 7

    for (int ch = 0; ch < 8; ++ch) {
        const float4* src = (const float4*)(feats + (size_t)ch * 9216);
        #pragma unroll
        for (int i = 0; i < 36; ++i)
            ((float4*)flds)[lane + i * 64] = src[lane + i * 64];
        __syncthreads();

        for (int tt = 0; tt < 1024; ++tt) {
            const int t = ch * 1024 + tt;
            const float f0 = __shfl(fv, 0), f1 = __shfl(fv, 1), f2 = __shfl(fv, 2);
            const float f3 = __shfl(fv, 3), f4 = __shfl(fv, 4), f5 = __shfl(fv, 5);
            const float f6 = __shfl(fv, 6), f7 = __shfl(fv, 7), f8 = __shfl(fv, 8);
            const float s0 = f0 + tr[0], s1 = f1 + tr[1], s2 = f2 + tr[2];
            const float s3 = f3 + tr[3], s4 = f4 + tr[4], s5 = f5 + tr[5];
            const float s6 = f6 + tr[6], s7 = f7 + tr[7], s8 = f8 + tr[8];
            const float mx = fmaxf(fmaxf(fmaxf(fmaxf(s0, s1), fmaxf(s2, s3)),
                                         fmaxf(fmaxf(s4, s5), fmaxf(s6, s7))), s8);
            const unsigned bits =
                (s0 >= mx ? 1u : 0u)   | (s1 >= mx ? 2u : 0u)   | (s2 >= mx ? 4u : 0u) |
                (s3 >= mx ? 8u : 0u)   | (s4 >= mx ? 16u : 0u)  | (s5 >= mx ? 32u : 0u) |
                (s6 >= mx ? 64u : 0u)  | (s7 >= mx ? 128u : 0u) | (s8 >= mx ? 256u : 0u);
            const int bi = __ffs(bits) - 1;
            const float feat = (lane < 9) ? flds[tt * 9 + lane] : 0.0f;
            fv = mx + feat;
            const unsigned long long b0 = __ballot(bi & 1);
            const unsigned long long b1 = __ballot(bi & 2);
            const unsigned long long b2 = __ballot(bi & 4);
            const unsigned long long b3 = __ballot(bi & 8);
            if (lane == 0) {
                bpw[t] = (b0 & 511ull) | ((b1 & 511ull) << 9) |
                         ((b2 & 511ull) << 18) | ((b3 & 511ull) << 27);
            }
        }
        __syncthreads();
    }

    const float term = fv + tstop;
    const float t0 = __shfl(term, 0), t1 = __shfl(term, 1), t2 = __shfl(term, 2);
    const float t3 = __shfl(term, 3), t4 = __shfl(term, 4), t5 = __shfl(term, 5);
    const float t6 = __shfl(term, 6), t7 = __shfl(term, 7), t8 = __shfl(term, 8);
    const float mxt = fmaxf(fmaxf(fmaxf(fmaxf(t0, t1), fmaxf(t2, t3)),
                                  fmaxf(fmaxf(t4, t5), fmaxf(t6, t7))), t8);
    const unsigned bitst =
        (t0 >= mxt ? 1u : 0u)   | (t1 >= mxt ? 2u : 0u)   | (t2 >= mxt ? 4u : 0u) |
        (t3 >= mxt ? 8u : 0u)   | (t4 >= mxt ? 16u : 0u)  | (t5 >= mxt ? 32u : 0u) |
        (t6 >= mxt ? 64u : 0u)  | (t7 >= mxt ? 128u : 0u) | (t8 >= mxt ? 256u : 0u);
    const int best = __ffs(bitst) - 1;

    if (lane == 0) {
        out[0] = mxt;
        int c = best;
        path_lds[T_SEQ - 1] = (unsigned char)c;
        for (int thi = T_SEQ - 2; thi >= 15; thi -= 16) {
            const int tlo = thi - 15;
            unsigned long long wbuf[16];
            #pragma unroll
            for (int i = 0; i < 16; ++i) wbuf[i] = bpw[tlo + 1 + i];
            #pragma unroll
            for (int i = 15; i >= 0; --i) {
                const unsigned long long wv = wbuf[i];
                c = (int)((wv >> c) & 1ull) |
                    ((int)((wv >> (9 + c)) & 1ull) << 1) |
                    ((int)((wv >> (18 + c)) & 1ull) << 2) |
                    ((int)((wv >> (27 + c)) & 1ull) << 3);
                path_lds[tlo + i] = (unsigned char)c;
            }
        }
        for (int t2i = 14; t2i >= 0; --t2i) {
            const unsigned long long wv = bpw[t2i + 1];
            c = (int)((wv >> c) & 1ull) |
                ((int)((wv >> (9 + c)) & 1ull) << 1) |
                ((int)((wv >> (18 + c)) & 1ull) << 2) |
                ((int)((wv >> (27 + c)) & 1ull) << 3);
            path_lds[t2i] = (unsigned char)c;
        }
    }
    __syncthreads();
    #pragma unroll 4
    for (int i = 0; i < T_SEQ / 64; ++i) {
        const int t = i * 64 + lane;
        out[1 + t] = (float)path_lds[t];
    }
}

// ------------------------------------------------------------------- launch
extern "C" void kernel_launch(void* const* d_in, const int* in_sizes, int n_in,
                              void* d_out, int out_size, void* d_ws, size_t ws_size,
                              hipStream_t stream)
{
    (void)in_sizes; (void)n_in; (void)out_size; (void)ws_size;

    const int*   sentence = (const int*)  d_in[0];
    const float* emb      = (const float*)d_in[1];
    const float* Wih_f    = (const float*)d_in[2];
    const float* Whh_f    = (const float*)d_in[3];
    const float* bih_f    = (const float*)d_in[4];
    const float* bhh_f    = (const float*)d_in[5];
    const float* Wih_b    = (const float*)d_in[6];
    const float* Whh_b    = (const float*)d_in[7];
    const float* bih_b    = (const float*)d_in[8];
    const float* bhh_b    = (const float*)d_in[9];
    const float* W_out    = (const float*)d_in[10];
    const float* b_out    = (const float*)d_in[11];
    const float* trans    = (const float*)d_in[12];

    float* ws      = (float*)d_ws;
    float* xprojb  = ws;                                        // 8192*4096
    float* hseq    = ws + (size_t)T_SEQ * 4096;                 // 2*8192*512
    float* feats   = hseq + (size_t)2 * T_SEQ * HDIM;           // 8192*9
    unsigned long long* bpw = (unsigned long long*)(feats + (size_t)T_SEQ * 9);

    // re-poison the h exchange buffer every launch (graph replay safety)
    hipMemsetAsync(hseq, 0x7F, (size_t)2 * T_SEQ * HDIM * sizeof(float), stream);

    gemm_xproj<<<dim3(64, 32), 256, 0, stream>>>(
        sentence, emb, Wih_f, Wih_b, bih_f, bhh_f, bih_b, bhh_b, xprojb);

    lstm_scan<<<dim3(64), 320, 0, stream>>>(
        xprojb, Whh_f, Whh_b, hseq);

    feats_kernel<<<dim3((T_SEQ * 9 + 255) / 256), 256, 0, stream>>>(
        hseq, W_out, b_out, feats);

    viterbi_kernel<<<dim3(1), 64, 0, stream>>>(feats, trans, bpw, (float*)d_out);
}